// Round 17
// baseline (289.617 us; speedup 1.0000x reference)
//
#include <hip/hip_runtime.h>
#include <hip/hip_bf16.h>
#include <math.h>

#define NTOK   16384
#define NEXP   64
#define HID    4096
#define KSEL   8
#define EPS    7.5e-5f
#define NSPLIT 4
#define KSZ    (HID / NSPLIT)

typedef __attribute__((ext_vector_type(8))) short short8;
typedef __attribute__((ext_vector_type(4))) float f32x4;

// d_out element offsets (f32 elements; int outputs stored as float values)
#define O_LOGITS 0u
#define O_PROBS  1048576u
#define O_TIDX   1179648u
#define O_GROUP  1310720u
#define O_IDX    1310784u
#define O_TPE    1441856u
#define O_LB     1441920u
#define O_ZL     1441921u

// ws byte offsets
#define W_CQ      0u          // 512 int: counts[q][e], q = row>>11
#define W_LSQP    8192u       // 256 f32 per-block z-loss partials
#define W_PSUM    81920u      // 256*128 f32 per-block half-tile probsum partials
#define W_FLAT    262144u     // 131072 int
#define W_WF      1048576u    // 1 MB: W packed as MFMA B-frags bf16 hi/lo
#define W_PART    2097152u    // NSPLIT x 4 MB f32 partials (ends at 18 MB)
// probe scrap (ws is ~1 GB; region 20 MB.. is dead)
#define W_SCRAP   20971520u   // cq2(2KB) | lsqp2(1KB@+4096) | psum2(128KB@+8192) | flat2(512KB@+147456) | out2(6MB@+1048576)
#define PART_STRIDE 1048576ull

// round-to-nearest-even f32 -> bf16 bits
__device__ __forceinline__ unsigned short f2bf(float f) {
  unsigned u = __float_as_uint(f);
  return (unsigned short)((u + 0x7fffu + ((u >> 16) & 1u)) >> 16);
}

__device__ __forceinline__ void gload16(const void* g, void* l) {
  __builtin_amdgcn_global_load_lds((const __attribute__((address_space(1))) unsigned int*)g,
                                   (__attribute__((address_space(3))) unsigned int*)l, 16, 0, 0);
}

// ---------------------------------------------------------------------------
// prep: pack W into MFMA B-frags (bf16 hi/lo) + zero counters.
__global__ __launch_bounds__(256) void k_prep(const float* __restrict__ w,
                                              short8* __restrict__ wf,
                                              int* __restrict__ cq) {
  const int kk   = blockIdx.x;
  const int nb   = threadIdx.x >> 6;
  const int lane = threadIdx.x & 63;
  const int n    = nb * 16 + (lane & 15);
  const int kb   = kk * 32 + (lane >> 4) * 8;
  const float4* wp = (const float4*)(w + (size_t)n * HID + kb);
  float4 f0 = wp[0], f1 = wp[1];
  float fv[8] = {f0.x, f0.y, f0.z, f0.w, f1.x, f1.y, f1.z, f1.w};
  short8 hi, lo;
#pragma unroll
  for (int j = 0; j < 8; ++j) {
    unsigned short h = f2bf(fv[j]);
    hi[j] = (short)h;
    float r = fv[j] - __uint_as_float((unsigned)h << 16);
    lo[j] = (short)f2bf(r);
  }
  size_t base = ((size_t)(kk * 4 + nb) * 2) * 64 + lane;
  wf[base] = hi;
  wf[base + 64] = lo;
  if (blockIdx.x == 0) {
    cq[threadIdx.x] = 0;
    cq[threadIdx.x + 256] = 0;
  }
}

// ---------------------------------------------------------------------------
// MFMA router GEMM (R8-exact, measured ~56us). wf LDS-shared (double-buffered,
// global_load_lds w16); x per-lane direct loads; one __syncthreads per chunk.
__global__ __launch_bounds__(256, 4) void k_gemm(const float* __restrict__ x,
                                                 const short8* __restrict__ wf,
                                                 float* __restrict__ part) {
  __shared__ short8 wl[2][512];   // 2 x 8 KB
  const int tid  = threadIdx.x;
  const int wv   = tid >> 6;
  const int lane = tid & 63;
  const int t0   = blockIdx.x * 64;
  const int k0   = blockIdx.y * KSZ;
  const int row  = t0 + wv * 16 + (lane & 15);

  const float* xp = x + (size_t)row * HID + k0 + (lane >> 4) * 8;
  const short8* wbase = wf + (size_t)(k0 >> 5) * 512;

  auto stage = [&](int c, int b) {
    const short8* src = wbase + (size_t)c * 512;
#pragma unroll
    for (int r = 0; r < 2; ++r) {
      const int o = r * 256 + wv * 64;       // wave-uniform LDS base
      gload16(src + o + lane, &wl[b][o]);    // lane*16B added by HW
    }
  };

  f32x4 acc[4] = {{0,0,0,0},{0,0,0,0},{0,0,0,0},{0,0,0,0}};

  stage(0, 0);
  __syncthreads();
  const int nch = KSZ >> 5;   // 32
  for (int c = 0; c < nch; ++c) {
    const int b = c & 1;
    if (c + 1 < nch) stage(c + 1, b ^ 1);

    const float4* xq = (const float4*)(xp + c * 32);
    float4 f0 = xq[0], f1 = xq[1];
    unsigned xb[8] = {__float_as_uint(f0.x), __float_as_uint(f0.y),
                      __float_as_uint(f0.z), __float_as_uint(f0.w),
                      __float_as_uint(f1.x), __float_as_uint(f1.y),
                      __float_as_uint(f1.z), __float_as_uint(f1.w)};
    union { unsigned u[4]; short8 s; } ua, ul;
#pragma unroll
    for (int p = 0; p < 4; ++p) {
      unsigned b0 = xb[2 * p], b1 = xb[2 * p + 1];
      ua.u[p] = __builtin_amdgcn_perm(b1, b0, 0x07060302u);
      float r0 = __uint_as_float(b0) - __uint_as_float(b0 & 0xffff0000u);
      float r1 = __uint_as_float(b1) - __uint_as_float(b1 & 0xffff0000u);
      unsigned t0b = __float_as_uint(r0), t1b = __float_as_uint(r1);
      t0b += 0x7fffu + ((t0b >> 16) & 1u);
      t1b += 0x7fffu + ((t1b >> 16) & 1u);
      ul.u[p] = __builtin_amdgcn_perm(t1b, t0b, 0x07060302u);
    }
    short8 ah = ua.s, al = ul.s;

#pragma unroll
    for (int nb = 0; nb < 4; ++nb) {
      short8 bh = wl[b][nb * 128 + lane];
      short8 bl = wl[b][nb * 128 + 64 + lane];
      acc[nb] = __builtin_amdgcn_mfma_f32_16x16x32_bf16(ah, bh, acc[nb], 0, 0, 0);
      acc[nb] = __builtin_amdgcn_mfma_f32_16x16x32_bf16(al, bh, acc[nb], 0, 0, 0);
      acc[nb] = __builtin_amdgcn_mfma_f32_16x16x32_bf16(ah, bl, acc[nb], 0, 0, 0);
    }
    __syncthreads();
  }

  float* p = part + (size_t)blockIdx.y * PART_STRIDE;
  const int mrow = t0 + wv * 16 + (lane >> 4) * 4;
  const int col  = lane & 15;
#pragma unroll
  for (int nb = 0; nb < 4; ++nb)
#pragma unroll
    for (int r = 0; r < 4; ++r)
      p[(size_t)(mrow + r) * 64 + nb * 16 + col] = acc[nb][r];
}

// ---------------------------------------------------------------------------
// Split-K reduce, 1024 blocks (R3-proven).
__global__ __launch_bounds__(256) void k_reduce(const float* __restrict__ part,
                                                float* __restrict__ out_logits) {
  unsigned i4 = blockIdx.x * 256u + threadIdx.x;
  const float4* p4 = (const float4*)part;
  float4 v = p4[i4];
#pragma unroll
  for (int s = 1; s < NSPLIT; ++s) {
    float4 a = p4[(size_t)s * (PART_STRIDE / 4) + i4];
    v.x += a.x; v.y += a.y; v.z += a.z; v.w += a.w;
  }
  ((float4*)out_logits)[i4] = v;
}

// ---------------------------------------------------------------------------
// Rowwise + in-block candidate-limited exact repair (R15-proven).
// PROBE NOTE: launched 3x this round; probe launches point out/cq/psum/lsqp/
// flat at dead scrap -> real results bit-identical, timing additive.
__global__ __launch_bounds__(256) void k_rowwise(const float* __restrict__ lg,
                                                 const float* __restrict__ x,
                                                 const float* __restrict__ w,
                                                 float* __restrict__ out,
                                                 int* __restrict__ cq,
                                                 float* __restrict__ psum,
                                                 float* __restrict__ lsqp,
                                                 int* __restrict__ flat) {
  __shared__ float tile[64][68];
  __shared__ float rmv[64], invv[64], val8s[64];
  __shared__ int   hist[64];
  __shared__ int   fl_rows[64];
  __shared__ int   fl_n;
  __shared__ unsigned long long candmask;
  __shared__ double cexact[64];
  const int bid  = blockIdx.x;
  const int tid  = threadIdx.x;
  const int wv   = tid >> 6;
  const int lane = tid & 63;
  const int t0   = bid * 64;
  if (tid < 64) hist[tid] = 0;
  if (tid == 0) fl_n = 0;

  {
    const size_t boff = (size_t)bid * 4096;
#pragma unroll
    for (int k = 0; k < 16; ++k) {
      int idx = k * 256 + tid;
      tile[idx >> 6][idx & 63] = lg[boff + idx];
    }
  }
  __syncthreads();

  if (wv == 1) {
    const int r = lane;
    float rm = -3.0e38f;
#pragma unroll
    for (int c4 = 0; c4 < 16; ++c4) {
      float4 f = *(float4*)&tile[r][c4 * 4];
      rm = fmaxf(rm, fmaxf(fmaxf(f.x, f.y), fmaxf(f.z, f.w)));
    }
    float se = 0.0f;
#pragma unroll
    for (int c4 = 0; c4 < 16; ++c4) {
      float4 f = *(float4*)&tile[r][c4 * 4];
      se += expf(f.x - rm) + expf(f.y - rm) + expf(f.z - rm) + expf(f.w - rm);
    }
    rmv[r] = rm; invv[r] = 1.0f / se;
    float lse = rm + logf(se);
    float l2 = lse * lse;
#pragma unroll
    for (int o = 32; o > 0; o >>= 1) l2 += __shfl_down(l2, o);
    if (lane == 0) lsqp[bid] = l2;
  }
  __syncthreads();

  if (wv == 0) {
    const unsigned t = t0 + lane;
    float val[9]; int idx[9];
#pragma unroll
    for (int j = 0; j < 9; ++j) { val[j] = -3.0e38f; idx[j] = 0; }
    bool flag = false;
#pragma unroll
    for (int c4 = 0; c4 < 16; ++c4) {
      float4 f = *(float4*)&tile[lane][c4 * 4];
      float fe[4] = {f.x, f.y, f.z, f.w};
#pragma unroll
      for (int jj = 0; jj < 4; ++jj) {
        float v = fe[jj];
        flag = flag || (fabsf(fabsf(v) - 2.0f) < EPS);
        float c = fminf(fmaxf(v, -2.0f), 2.0f);
        int id = c4 * 4 + jj;
#pragma unroll
        for (int j = 0; j < 9; ++j) {
          bool sw = c > val[j];
          float tv = sw ? val[j] : c; int ti = sw ? idx[j] : id;
          val[j] = sw ? c : val[j];   idx[j] = sw ? id : idx[j];
          c = tv; id = ti;
        }
      }
    }
    val8s[lane] = val[8];
#pragma unroll
    for (int j = 0; j < 8; ++j) {
      float gap = val[j] - val[j + 1];
      bool bothclip = (val[j] == val[j + 1]) && (fabsf(val[j]) == 2.0f);
      flag = flag || (gap < EPS && !bothclip);
    }
    if (!flag) {
      float m = val[0], pe[8], sum = 0.0f;
#pragma unroll
      for (int j = 0; j < 8; ++j) { pe[j] = expf(val[j] - m); sum += pe[j]; }
      float inv = 1.0f / sum;
      *(float4*)&out[O_PROBS + (size_t)t * 8]     = make_float4(pe[0]*inv, pe[1]*inv, pe[2]*inv, pe[3]*inv);
      *(float4*)&out[O_PROBS + (size_t)t * 8 + 4] = make_float4(pe[4]*inv, pe[5]*inv, pe[6]*inv, pe[7]*inv);
      *(float4*)&out[O_TIDX + (size_t)t * 8]      = make_float4((float)idx[0], (float)idx[1], (float)idx[2], (float)idx[3]);
      *(float4*)&out[O_TIDX + (size_t)t * 8 + 4]  = make_float4((float)idx[4], (float)idx[5], (float)idx[6], (float)idx[7]);
      *(int4*)&flat[(size_t)t * 8]     = make_int4(idx[0], idx[1], idx[2], idx[3]);
      *(int4*)&flat[(size_t)t * 8 + 4] = make_int4(idx[4], idx[5], idx[6], idx[7]);
#pragma unroll
      for (int j = 0; j < 8; ++j) atomicAdd(&hist[idx[j]], 1);
    } else {
      int sl = atomicAdd(&fl_n, 1);
      fl_rows[sl] = lane;
    }
  } else if (wv == 2 || wv == 3) {
    const int e = lane, half = wv - 2;
    float s = 0.0f;
#pragma unroll
    for (int r = 0; r < 32; ++r) {
      int rr = half * 32 + r;
      s += expf(tile[rr][e] - rmv[rr]) * invv[rr];
    }
    psum[(size_t)bid * 128 + half * 64 + e] = s;
  }
  __syncthreads();

  for (int i = 0; i < fl_n; ++i) {
    const int r = fl_rows[i];
    if (wv == 0) {
      float c = fminf(fmaxf(tile[r][lane], -2.0f), 2.0f);
      bool cnd = (c >= val8s[r] - 3.0f * EPS);
      unsigned long long m = __ballot(cnd);
      if (lane == 0) candmask = m;
    }
    __syncthreads();
    const unsigned long long m = candmask;
    const float* xr = x + (size_t)(t0 + r) * HID;
    {
      int ord = 0;
      for (int e = 0; e < 64; ++e) {
        if ((m >> e) & 1ull) {
          if ((ord & 3) == wv) {
            const float* wr = w + (size_t)e * HID;
            double p0 = 0.0, p1 = 0.0, p2 = 0.0, p3 = 0.0;
            const int kb = lane * 64;
            for (int k = kb; k < kb + 64; k += 4) {
              float4 xv = *(const float4*)&xr[k];
              float4 wv4 = *(const float4*)&wr[k];
              p0 = fma((double)xv.x, (double)wv4.x, p0);
              p1 = fma((double)xv.y, (double)wv4.y, p1);
              p2 = fma((double)xv.z, (double)wv4.z, p2);
              p3 = fma((double)xv.w, (double)wv4.w, p3);
            }
            double p = (p0 + p1) + (p2 + p3);
#pragma unroll
            for (int o = 32; o > 0; o >>= 1) p += __shfl_down(p, o);
            if (lane == 0) cexact[e] = fmin(fmax(p, -2.0), 2.0);
          }
          ord++;
        }
      }
    }
    __syncthreads();
    if (tid == r) {
      double val[8]; int idx[8];
#pragma unroll
      for (int j = 0; j < 8; ++j) { val[j] = -1.0e300; idx[j] = 0; }
      for (int e = 0; e < 64; ++e) {
        if (!((m >> e) & 1ull)) continue;
        double c = cexact[e];
        int id = e;
#pragma unroll
        for (int j = 0; j < 8; ++j) {
          bool sw = c > val[j];
          double tv = sw ? val[j] : c; int ti = sw ? idx[j] : id;
          val[j] = sw ? c : val[j];    idx[j] = sw ? id : idx[j];
          c = tv; id = ti;
        }
      }
      float mm = (float)val[0], pe[8], sum = 0.0f;
#pragma unroll
      for (int j = 0; j < 8; ++j) { pe[j] = expf((float)val[j] - mm); sum += pe[j]; }
      float inv = 1.0f / sum;
      const unsigned t = t0 + r;
#pragma unroll
      for (int j = 0; j < 8; ++j) {
        out[O_PROBS + (size_t)t * 8 + j] = pe[j] * inv;
        out[O_TIDX  + (size_t)t * 8 + j] = (float)idx[j];
        flat[(size_t)t * 8 + j] = idx[j];
        atomicAdd(&hist[idx[j]], 1);
      }
    }
    __syncthreads();
  }

  if (tid < 64) atomicAdd(&cq[(bid >> 5) * 64 + tid], hist[tid]);
}

// ---------------------------------------------------------------------------
// Stable counting-sort scatter + inlined finalize (R15-proven).
// Idempotent (pure function of flat/cq/psum/lsqp) -> launched 2x as probe.
__global__ __launch_bounds__(256) void k_dispatch(const int* __restrict__ flat,
                                                  const int* __restrict__ cq,
                                                  const float* __restrict__ psum,
                                                  const float* __restrict__ lsqp,
                                                  float* __restrict__ out) {
  __shared__ int ctot[64];
  __shared__ int sbase;
  __shared__ int wcs[4];
  __shared__ float gsum[4][64];
  const int e = blockIdx.x >> 3;
  const int q = blockIdx.x & 7;
  const int tid = threadIdx.x;
  const int lane = tid & 63;
  const int wv = tid >> 6;

  if (tid < 64) {
    int tpe = 0;
#pragma unroll
    for (int qq = 0; qq < 8; ++qq) tpe += cq[qq * 64 + tid];
    ctot[tid] = tpe;
  }
  __syncthreads();
  if (tid == 0) {
    int b = 0;
    for (int i = 0; i < e; ++i) b += ctot[i];
    for (int qq = 0; qq < q; ++qq) b += cq[qq * 64 + e];
    sbase = b;
  }

  if (blockIdx.x == 0) {
    const int e2 = tid & 63, g = tid >> 6;
    float ps = 0.0f;
    for (int b = g; b < 256; b += 4) ps += psum[(size_t)b * 128 + e2] + psum[(size_t)b * 128 + 64 + e2];
    gsum[g][e2] = ps;
    __syncthreads();
    if (tid < 64) {
      int incl = 0;
      for (int i = 0; i <= tid; ++i) incl += ctot[i];
      int tpe = ctot[tid];
      out[O_TPE + tid]   = (float)tpe;
      out[O_GROUP + tid] = (float)incl;
      float pst = (gsum[0][tid] + gsum[1][tid]) + (gsum[2][tid] + gsum[3][tid]);
      float term = ((float)tpe / 131072.0f) * (pst / 16384.0f) * 64.0f;
#pragma unroll
      for (int o2 = 32; o2 > 0; o2 >>= 1) term += __shfl_down(term, o2);
      float zs = (lsqp[tid * 4] + lsqp[tid * 4 + 1]) + (lsqp[tid * 4 + 2] + lsqp[tid * 4 + 3]);
#pragma unroll
      for (int o2 = 32; o2 > 0; o2 >>= 1) zs += __shfl_down(zs, o2);
      if (tid == 0) { out[O_LB] = term; out[O_ZL] = zs / 16384.0f; }
    }
  }
  __syncthreads();

  int base = sbase;
  const int seg0 = q * 16384;
  for (int c0 = 0; c0 < 16384; c0 += 2048) {
    const int j0 = seg0 + c0 + tid * 8;
    const int4* f4 = reinterpret_cast<const int4*>(flat + j0);
    int4 a = f4[0], b = f4[1];
    int v[8] = {a.x, a.y, a.z, a.w, b.x, b.y, b.z, b.w};
    int mcnt = 0;
#pragma unroll
    for (int k = 0; k < 8; ++k) mcnt += (v[k] == e) ? 1 : 0;
    int sc = mcnt;
#pragma unroll
    for (int o = 1; o < 64; o <<= 1) {
      int nn = __shfl_up(sc, o);
      if (lane >= o) sc += nn;
    }
    int excl = sc - mcnt;
    if (lane == 63) wcs[wv] = sc;
    __syncthreads();
    int woff = 0, tot = 0;
#pragma unroll
    for (int i = 0; i < 4; ++i) { int ci = wcs[i]; woff += (i < wv) ? ci : 0; tot += ci; }
    int pos = base + woff + excl;
#pragma unroll
    for (int k = 0; k < 8; ++k) {
      if (v[k] == e) { out[O_IDX + pos] = (float)(j0 + k); pos++; }
    }
    base += tot;
    __syncthreads();
  }
}

// ---------------------------------------------------------------------------
extern "C" void kernel_launch(void* const* d_in, const int* in_sizes, int n_in,
                              void* d_out, int out_size, void* d_ws, size_t ws_size,
                              hipStream_t stream) {
  (void)in_sizes; (void)n_in; (void)out_size; (void)ws_size;
  const float* x  = (const float*)d_in[0];
  const float* Wm = (const float*)d_in[1];
  float* out = (float*)d_out;
  char*  ws  = (char*)d_ws;

  int*    cq     = (int*)(ws + W_CQ);
  float*  lsqp   = (float*)(ws + W_LSQP);
  float*  psum   = (float*)(ws + W_PSUM);
  int*    flat   = (int*)(ws + W_FLAT);
  short8* wf     = (short8*)(ws + W_WF);
  float*  part   = (float*)(ws + W_PART);

  // probe scrap (dead memory; never read)
  int*    cq2    = (int*)(ws + W_SCRAP);
  float*  lsqp2  = (float*)(ws + W_SCRAP + 4096);
  float*  psum2  = (float*)(ws + W_SCRAP + 8192);
  int*    flat2  = (int*)(ws + W_SCRAP + 147456);
  float*  out2   = (float*)(ws + W_SCRAP + 1048576);

  k_prep    <<<dim3(128), dim3(256), 0, stream>>>(Wm, wf, cq);
  k_gemm    <<<dim3(NTOK / 64, NSPLIT), dim3(256), 0, stream>>>(x, wf, part);
  k_reduce  <<<dim3(1024), dim3(256), 0, stream>>>(part, out + O_LOGITS);
  k_rowwise <<<dim3(256), dim3(256), 0, stream>>>(out + O_LOGITS, x, Wm, out, cq, psum, lsqp, flat);
  // TIMING PROBES: 2x rowwise into scrap (reads real logits; writes discarded),
  // 1x extra dispatch (idempotent). Delta = 2*T_row + T_disp.
  k_rowwise <<<dim3(256), dim3(256), 0, stream>>>(out + O_LOGITS, x, Wm, out2, cq2, psum2, lsqp2, flat2);
  k_rowwise <<<dim3(256), dim3(256), 0, stream>>>(out + O_LOGITS, x, Wm, out2, cq2, psum2, lsqp2, flat2);
  k_dispatch<<<dim3(512), dim3(256), 0, stream>>>(flat, cq, psum, lsqp, out);
  k_dispatch<<<dim3(512), dim3(256), 0, stream>>>(flat, cq, psum, lsqp, out);
}

// Round 18
// 170.280 us; speedup vs baseline: 1.7008x; 1.7008x over previous
//
#include <hip/hip_runtime.h>
#include <hip/hip_bf16.h>
#include <math.h>

#define NTOK   16384
#define NEXP   64
#define HID    4096
#define KSEL   8
#define EPS    7.5e-5f
#define NSPLIT 4
#define KSZ    (HID / NSPLIT)

typedef __attribute__((ext_vector_type(8))) short short8;
typedef __attribute__((ext_vector_type(4))) float f32x4;

// d_out element offsets (f32 elements; int outputs stored as float values)
#define O_LOGITS 0u
#define O_PROBS  1048576u
#define O_TIDX   1179648u
#define O_GROUP  1310720u
#define O_IDX    1310784u
#define O_TPE    1441856u
#define O_LB     1441920u
#define O_ZL     1441921u

// ws byte offsets
#define W_LSQP    4096u       // 256 f32 per-block z-loss partials
#define W_CBE     8192u       // 256*64 int per-block expert counts
#define W_PREF    73728u      // 256*64 int global scatter bases
#define W_PSUM    262144u     // 256*128 f32 per-block half-tile probsum partials
#define W_FLAT    524288u     // 131072 int final expert ids
#define W_RNK     1048576u    // 131072 int within-block stable ranks
#define W_WF      2097152u    // 1 MB: W packed as MFMA B-frags bf16 hi/lo
#define W_PART    4194304u    // NSPLIT x 4 MB f32 partials
#define PART_STRIDE 1048576ull

// round-to-nearest-even f32 -> bf16 bits
__device__ __forceinline__ unsigned short f2bf(float f) {
  unsigned u = __float_as_uint(f);
  return (unsigned short)((u + 0x7fffu + ((u >> 16) & 1u)) >> 16);
}

__device__ __forceinline__ void gload16(const void* g, void* l) {
  __builtin_amdgcn_global_load_lds((const __attribute__((address_space(1))) unsigned int*)g,
                                   (__attribute__((address_space(3))) unsigned int*)l, 16, 0, 0);
}

// ---------------------------------------------------------------------------
// prep: pack W into MFMA B-frags (bf16 hi/lo). No counters needed anymore.
__global__ __launch_bounds__(256) void k_prep(const float* __restrict__ w,
                                              short8* __restrict__ wf) {
  const int kk   = blockIdx.x;
  const int nb   = threadIdx.x >> 6;
  const int lane = threadIdx.x & 63;
  const int n    = nb * 16 + (lane & 15);
  const int kb   = kk * 32 + (lane >> 4) * 8;
  const float4* wp = (const float4*)(w + (size_t)n * HID + kb);
  float4 f0 = wp[0], f1 = wp[1];
  float fv[8] = {f0.x, f0.y, f0.z, f0.w, f1.x, f1.y, f1.z, f1.w};
  short8 hi, lo;
#pragma unroll
  for (int j = 0; j < 8; ++j) {
    unsigned short h = f2bf(fv[j]);
    hi[j] = (short)h;
    float r = fv[j] - __uint_as_float((unsigned)h << 16);
    lo[j] = (short)f2bf(r);
  }
  size_t base = ((size_t)(kk * 4 + nb) * 2) * 64 + lane;
  wf[base] = hi;
  wf[base + 64] = lo;
}

// ---------------------------------------------------------------------------
// MFMA router GEMM (R8-exact, measured ~56us). wf LDS-shared (double-buffered,
// global_load_lds w16); x per-lane direct loads; one __syncthreads per chunk.
__global__ __launch_bounds__(256, 4) void k_gemm(const float* __restrict__ x,
                                                 const short8* __restrict__ wf,
                                                 float* __restrict__ part) {
  __shared__ short8 wl[2][512];   // 2 x 8 KB
  const int tid  = threadIdx.x;
  const int wv   = tid >> 6;
  const int lane = tid & 63;
  const int t0   = blockIdx.x * 64;
  const int k0   = blockIdx.y * KSZ;
  const int row  = t0 + wv * 16 + (lane & 15);

  const float* xp = x + (size_t)row * HID + k0 + (lane >> 4) * 8;
  const short8* wbase = wf + (size_t)(k0 >> 5) * 512;

  auto stage = [&](int c, int b) {
    const short8* src = wbase + (size_t)c * 512;
#pragma unroll
    for (int r = 0; r < 2; ++r) {
      const int o = r * 256 + wv * 64;       // wave-uniform LDS base
      gload16(src + o + lane, &wl[b][o]);    // lane*16B added by HW
    }
  };

  f32x4 acc[4] = {{0,0,0,0},{0,0,0,0},{0,0,0,0},{0,0,0,0}};

  stage(0, 0);
  __syncthreads();
  const int nch = KSZ >> 5;   // 32
  for (int c = 0; c < nch; ++c) {
    const int b = c & 1;
    if (c + 1 < nch) stage(c + 1, b ^ 1);

    const float4* xq = (const float4*)(xp + c * 32);
    float4 f0 = xq[0], f1 = xq[1];
    unsigned xb[8] = {__float_as_uint(f0.x), __float_as_uint(f0.y),
                      __float_as_uint(f0.z), __float_as_uint(f0.w),
                      __float_as_uint(f1.x), __float_as_uint(f1.y),
                      __float_as_uint(f1.z), __float_as_uint(f1.w)};
    union { unsigned u[4]; short8 s; } ua, ul;
#pragma unroll
    for (int p = 0; p < 4; ++p) {
      unsigned b0 = xb[2 * p], b1 = xb[2 * p + 1];
      ua.u[p] = __builtin_amdgcn_perm(b1, b0, 0x07060302u);
      float r0 = __uint_as_float(b0) - __uint_as_float(b0 & 0xffff0000u);
      float r1 = __uint_as_float(b1) - __uint_as_float(b1 & 0xffff0000u);
      unsigned t0b = __float_as_uint(r0), t1b = __float_as_uint(r1);
      t0b += 0x7fffu + ((t0b >> 16) & 1u);
      t1b += 0x7fffu + ((t1b >> 16) & 1u);
      ul.u[p] = __builtin_amdgcn_perm(t1b, t0b, 0x07060302u);
    }
    short8 ah = ua.s, al = ul.s;

#pragma unroll
    for (int nb = 0; nb < 4; ++nb) {
      short8 bh = wl[b][nb * 128 + lane];
      short8 bl = wl[b][nb * 128 + 64 + lane];
      acc[nb] = __builtin_amdgcn_mfma_f32_16x16x32_bf16(ah, bh, acc[nb], 0, 0, 0);
      acc[nb] = __builtin_amdgcn_mfma_f32_16x16x32_bf16(al, bh, acc[nb], 0, 0, 0);
      acc[nb] = __builtin_amdgcn_mfma_f32_16x16x32_bf16(ah, bl, acc[nb], 0, 0, 0);
    }
    __syncthreads();
  }

  float* p = part + (size_t)blockIdx.y * PART_STRIDE;
  const int mrow = t0 + wv * 16 + (lane >> 4) * 4;
  const int col  = lane & 15;
#pragma unroll
  for (int nb = 0; nb < 4; ++nb)
#pragma unroll
    for (int r = 0; r < 4; ++r)
      p[(size_t)(mrow + r) * 64 + nb * 16 + col] = acc[nb][r];
}

// ---------------------------------------------------------------------------
// Split-K reduce, 1024 blocks (R3-proven).
__global__ __launch_bounds__(256) void k_reduce(const float* __restrict__ part,
                                                float* __restrict__ out_logits) {
  unsigned i4 = blockIdx.x * 256u + threadIdx.x;
  const float4* p4 = (const float4*)part;
  float4 v = p4[i4];
#pragma unroll
  for (int s = 1; s < NSPLIT; ++s) {
    float4 a = p4[(size_t)s * (PART_STRIDE / 4) + i4];
    v.x += a.x; v.y += a.y; v.z += a.z; v.w += a.w;
  }
  ((float4*)out_logits)[i4] = v;
}

// ---------------------------------------------------------------------------
// Rowwise + in-block repair + STABLE RANK computation (replaces dispatch's
// redundant scans). 256 blocks x 256 thr. After final ids are known (incl.
// repair), 4 waves each scan one 128-elem quarter (expert-per-lane, broadcast
// LDS reads) -> local ranks + quarter counts; rank = local + quarter prefix.
// Emits flat ids, per-element ranks, and per-block expert counts cbe.
__global__ __launch_bounds__(256) void k_rowwise(const float* __restrict__ lg,
                                                 const float* __restrict__ x,
                                                 const float* __restrict__ w,
                                                 float* __restrict__ out,
                                                 float* __restrict__ psum,
                                                 float* __restrict__ lsqp,
                                                 int* __restrict__ flat,
                                                 int* __restrict__ rnk_g,
                                                 int* __restrict__ cbe) {
  __shared__ float tile[64][68];
  __shared__ float rmv[64], invv[64], val8s[64];
  __shared__ int   ids[512];
  __shared__ int   rnk_lds[512];
  __shared__ int   cntq[4][64];
  __shared__ int   fl_rows[64];
  __shared__ int   fl_n;
  __shared__ unsigned long long candmask;
  __shared__ double cexact[64];
  const int bid  = blockIdx.x;
  const int tid  = threadIdx.x;
  const int wv   = tid >> 6;
  const int lane = tid & 63;
  const int t0   = bid * 64;
  if (tid == 0) fl_n = 0;

  {
    const size_t boff = (size_t)bid * 4096;
#pragma unroll
    for (int k = 0; k < 16; ++k) {
      int idx = k * 256 + tid;
      tile[idx >> 6][idx & 63] = lg[boff + idx];
    }
  }
  __syncthreads();

  if (wv == 1) {
    const int r = lane;
    float rm = -3.0e38f;
#pragma unroll
    for (int c4 = 0; c4 < 16; ++c4) {
      float4 f = *(float4*)&tile[r][c4 * 4];
      rm = fmaxf(rm, fmaxf(fmaxf(f.x, f.y), fmaxf(f.z, f.w)));
    }
    float se = 0.0f;
#pragma unroll
    for (int c4 = 0; c4 < 16; ++c4) {
      float4 f = *(float4*)&tile[r][c4 * 4];
      se += expf(f.x - rm) + expf(f.y - rm) + expf(f.z - rm) + expf(f.w - rm);
    }
    rmv[r] = rm; invv[r] = 1.0f / se;
    float lse = rm + logf(se);
    float l2 = lse * lse;
#pragma unroll
    for (int o = 32; o > 0; o >>= 1) l2 += __shfl_down(l2, o);
    if (lane == 0) lsqp[bid] = l2;
  }
  __syncthreads();

  if (wv == 0) {
    const unsigned t = t0 + lane;
    float val[9]; int idx[9];
#pragma unroll
    for (int j = 0; j < 9; ++j) { val[j] = -3.0e38f; idx[j] = 0; }
    bool flag = false;
#pragma unroll
    for (int c4 = 0; c4 < 16; ++c4) {
      float4 f = *(float4*)&tile[lane][c4 * 4];
      float fe[4] = {f.x, f.y, f.z, f.w};
#pragma unroll
      for (int jj = 0; jj < 4; ++jj) {
        float v = fe[jj];
        flag = flag || (fabsf(fabsf(v) - 2.0f) < EPS);
        float c = fminf(fmaxf(v, -2.0f), 2.0f);
        int id = c4 * 4 + jj;
#pragma unroll
        for (int j = 0; j < 9; ++j) {
          bool sw = c > val[j];
          float tv = sw ? val[j] : c; int ti = sw ? idx[j] : id;
          val[j] = sw ? c : val[j];   idx[j] = sw ? id : idx[j];
          c = tv; id = ti;
        }
      }
    }
    val8s[lane] = val[8];
#pragma unroll
    for (int j = 0; j < 8; ++j) {
      float gap = val[j] - val[j + 1];
      bool bothclip = (val[j] == val[j + 1]) && (fabsf(val[j]) == 2.0f);
      flag = flag || (gap < EPS && !bothclip);
    }
    if (!flag) {
      float m = val[0], pe[8], sum = 0.0f;
#pragma unroll
      for (int j = 0; j < 8; ++j) { pe[j] = expf(val[j] - m); sum += pe[j]; }
      float inv = 1.0f / sum;
      *(float4*)&out[O_PROBS + (size_t)t * 8]     = make_float4(pe[0]*inv, pe[1]*inv, pe[2]*inv, pe[3]*inv);
      *(float4*)&out[O_PROBS + (size_t)t * 8 + 4] = make_float4(pe[4]*inv, pe[5]*inv, pe[6]*inv, pe[7]*inv);
      *(float4*)&out[O_TIDX + (size_t)t * 8]      = make_float4((float)idx[0], (float)idx[1], (float)idx[2], (float)idx[3]);
      *(float4*)&out[O_TIDX + (size_t)t * 8 + 4]  = make_float4((float)idx[4], (float)idx[5], (float)idx[6], (float)idx[7]);
      *(int4*)&flat[(size_t)t * 8]     = make_int4(idx[0], idx[1], idx[2], idx[3]);
      *(int4*)&flat[(size_t)t * 8 + 4] = make_int4(idx[4], idx[5], idx[6], idx[7]);
#pragma unroll
      for (int j = 0; j < 8; ++j) ids[lane * 8 + j] = idx[j];
    } else {
      int sl = atomicAdd(&fl_n, 1);
      fl_rows[sl] = lane;
    }
  } else if (wv == 2 || wv == 3) {
    const int e = lane, half = wv - 2;
    float s = 0.0f;
#pragma unroll
    for (int r = 0; r < 32; ++r) {
      int rr = half * 32 + r;
      s += expf(tile[rr][e] - rmv[rr]) * invv[rr];
    }
    psum[(size_t)bid * 128 + half * 64 + e] = s;
  }
  __syncthreads();

  // ---- in-block repair of flagged rows (candidate-limited exact f64) ----
  for (int i = 0; i < fl_n; ++i) {
    const int r = fl_rows[i];
    if (wv == 0) {
      float c = fminf(fmaxf(tile[r][lane], -2.0f), 2.0f);
      bool cnd = (c >= val8s[r] - 3.0f * EPS);
      unsigned long long m = __ballot(cnd);
      if (lane == 0) candmask = m;
    }
    __syncthreads();
    const unsigned long long m = candmask;
    const float* xr = x + (size_t)(t0 + r) * HID;
    {
      int ord = 0;
      for (int e = 0; e < 64; ++e) {
        if ((m >> e) & 1ull) {
          if ((ord & 3) == wv) {
            const float* wr = w + (size_t)e * HID;
            double p0 = 0.0, p1 = 0.0, p2 = 0.0, p3 = 0.0;
            const int kb = lane * 64;
            for (int k = kb; k < kb + 64; k += 4) {
              float4 xv = *(const float4*)&xr[k];
              float4 wv4 = *(const float4*)&wr[k];
              p0 = fma((double)xv.x, (double)wv4.x, p0);
              p1 = fma((double)xv.y, (double)wv4.y, p1);
              p2 = fma((double)xv.z, (double)wv4.z, p2);
              p3 = fma((double)xv.w, (double)wv4.w, p3);
            }
            double p = (p0 + p1) + (p2 + p3);
#pragma unroll
            for (int o = 32; o > 0; o >>= 1) p += __shfl_down(p, o);
            if (lane == 0) cexact[e] = fmin(fmax(p, -2.0), 2.0);
          }
          ord++;
        }
      }
    }
    __syncthreads();
    if (tid == r) {
      double val[8]; int idx[8];
#pragma unroll
      for (int j = 0; j < 8; ++j) { val[j] = -1.0e300; idx[j] = 0; }
      for (int e = 0; e < 64; ++e) {
        if (!((m >> e) & 1ull)) continue;
        double c = cexact[e];
        int id = e;
#pragma unroll
        for (int j = 0; j < 8; ++j) {
          bool sw = c > val[j];
          double tv = sw ? val[j] : c; int ti = sw ? idx[j] : id;
          val[j] = sw ? c : val[j];    idx[j] = sw ? id : idx[j];
          c = tv; id = ti;
        }
      }
      float mm = (float)val[0], pe[8], sum = 0.0f;
#pragma unroll
      for (int j = 0; j < 8; ++j) { pe[j] = expf((float)val[j] - mm); sum += pe[j]; }
      float inv = 1.0f / sum;
      const unsigned t = t0 + r;
#pragma unroll
      for (int j = 0; j < 8; ++j) {
        out[O_PROBS + (size_t)t * 8 + j] = pe[j] * inv;
        out[O_TIDX  + (size_t)t * 8 + j] = (float)idx[j];
        flat[(size_t)t * 8 + j] = idx[j];
        ids[r * 8 + j] = idx[j];
      }
    }
    __syncthreads();
  }

  // ---- stable rank scan: wave wv scans quarter [wv*128, +128), lane=expert ----
  {
    int cnt = 0;
    const int base = wv * 128;
    for (int i = base; i < base + 128; ++i) {
      int id = ids[i];               // broadcast read (same addr across lanes)
      if (id == lane) { rnk_lds[i] = cnt; cnt++; }
    }
    cntq[wv][lane] = cnt;
  }
  __syncthreads();

  // write ranks (+quarter prefix) and per-block counts
#pragma unroll
  for (int k2 = 0; k2 < 2; ++k2) {
    const int i = tid * 2 + k2;
    const int e = ids[i];
    int r = rnk_lds[i];
    const int q = i >> 7;
    for (int wq = 0; wq < q; ++wq) r += cntq[wq][e];
    rnk_g[(size_t)bid * 512 + i] = r;
  }
  if (tid < 64)
    cbe[bid * 64 + tid] = cntq[0][tid] + cntq[1][tid] + cntq[2][tid] + cntq[3][tid];
}

// ---------------------------------------------------------------------------
// Scan + finalize: per-expert prefix over 256 block-counts -> global scatter
// bases; tokens_per_expert / group_indices / lb_loss / z_loss. 1 block.
__global__ __launch_bounds__(256) void k_scan(const int* __restrict__ cbe,
                                              const float* __restrict__ psum,
                                              const float* __restrict__ lsqp,
                                              int* __restrict__ pref,
                                              float* __restrict__ out) {
  __shared__ int ctot[64];
  __shared__ float gsum[4][64];
  const int tid = threadIdx.x;
  const int e = tid & 63, g = tid >> 6;

  float ps = 0.0f;
  for (int b = g; b < 256; b += 4) ps += psum[(size_t)b * 128 + e] + psum[(size_t)b * 128 + 64 + e];
  gsum[g][e] = ps;

  if (tid < 64) {
    int s = 0;
    for (int b = 0; b < 256; ++b) s += cbe[b * 64 + tid];
    ctot[tid] = s;
  }
  __syncthreads();

  if (tid < 64) {
    int incl = 0;
    for (int i = 0; i <= tid; ++i) incl += ctot[i];
    const int tpe = ctot[tid];
    out[O_TPE + tid]   = (float)tpe;
    out[O_GROUP + tid] = (float)incl;
    int run = incl - tpe;                       // exclusive expert base
    for (int b = 0; b < 256; ++b) { pref[b * 64 + tid] = run; run += cbe[b * 64 + tid]; }

    float pst = (gsum[0][tid] + gsum[1][tid]) + (gsum[2][tid] + gsum[3][tid]);
    float term = ((float)tpe / 131072.0f) * (pst / 16384.0f) * 64.0f;
#pragma unroll
    for (int o2 = 32; o2 > 0; o2 >>= 1) term += __shfl_down(term, o2);
    float zs = (lsqp[tid * 4] + lsqp[tid * 4 + 1]) + (lsqp[tid * 4 + 2] + lsqp[tid * 4 + 3]);
#pragma unroll
    for (int o2 = 32; o2 > 0; o2 >>= 1) zs += __shfl_down(zs, o2);
    if (tid == 0) { out[O_LB] = term; out[O_ZL] = zs / 16384.0f; }
  }
}

// ---------------------------------------------------------------------------
// Elementwise scatter: pos = pref[block][e] + rank. 512 blocks x 256 thr.
__global__ __launch_bounds__(256) void k_scatter(const int* __restrict__ flat,
                                                 const int* __restrict__ rnk,
                                                 const int* __restrict__ pref,
                                                 float* __restrict__ out) {
  const int j = blockIdx.x * 256 + threadIdx.x;
  const int e = flat[j];
  const int pos = pref[(j >> 9) * 64 + e] + rnk[j];
  out[O_IDX + pos] = (float)j;
}

// ---------------------------------------------------------------------------
extern "C" void kernel_launch(void* const* d_in, const int* in_sizes, int n_in,
                              void* d_out, int out_size, void* d_ws, size_t ws_size,
                              hipStream_t stream) {
  (void)in_sizes; (void)n_in; (void)out_size; (void)ws_size;
  const float* x  = (const float*)d_in[0];
  const float* Wm = (const float*)d_in[1];
  float* out = (float*)d_out;
  char*  ws  = (char*)d_ws;

  float*  lsqp   = (float*)(ws + W_LSQP);
  int*    cbe    = (int*)(ws + W_CBE);
  int*    pref   = (int*)(ws + W_PREF);
  float*  psum   = (float*)(ws + W_PSUM);
  int*    flat   = (int*)(ws + W_FLAT);
  int*    rnk    = (int*)(ws + W_RNK);
  short8* wf     = (short8*)(ws + W_WF);
  float*  part   = (float*)(ws + W_PART);

  k_prep   <<<dim3(128),  dim3(256), 0, stream>>>(Wm, wf);
  k_gemm   <<<dim3(NTOK / 64, NSPLIT), dim3(256), 0, stream>>>(x, wf, part);
  k_reduce <<<dim3(1024), dim3(256), 0, stream>>>(part, out + O_LOGITS);
  k_rowwise<<<dim3(256),  dim3(256), 0, stream>>>(out + O_LOGITS, x, Wm, out, psum, lsqp, flat, rnk, cbe);
  k_scan   <<<dim3(1),    dim3(256), 0, stream>>>(cbe, psum, lsqp, pref, out);
  k_scatter<<<dim3(512),  dim3(256), 0, stream>>>(flat, rnk, pref, out);
}

// Round 19
// 145.073 us; speedup vs baseline: 1.9964x; 1.1738x over previous
//
#include <hip/hip_runtime.h>
#include <hip/hip_bf16.h>
#include <math.h>

#define NTOK   16384
#define NEXP   64
#define HID    4096
#define KSEL   8
#define EPS    7.5e-5f
#define NSPLIT 4
#define KSZ    (HID / NSPLIT)

typedef __attribute__((ext_vector_type(8))) short short8;
typedef __attribute__((ext_vector_type(4))) float f32x4;

// d_out element offsets (f32 elements; int outputs stored as float values)
#define O_LOGITS 0u
#define O_PROBS  1048576u
#define O_TIDX   1179648u
#define O_GROUP  1310720u
#define O_IDX    1310784u
#define O_TPE    1441856u
#define O_LB     1441920u
#define O_ZL     1441921u

// ws byte offsets
#define W_LSQP    4096u       // 256 f32 per-block z-loss partials
#define W_CBE     8192u       // 256*64 int per-block expert counts
#define W_PREF    73728u      // 256*64 int global scatter bases
#define W_PSUM    262144u     // 256*128 f32 per-block half-tile probsum partials
#define W_FLAT    524288u     // 131072 int final expert ids
#define W_RNK     1048576u    // 131072 int within-block stable ranks
#define W_WF      2097152u    // 1 MB: W packed as MFMA B-frags bf16 hi/lo
#define W_PART    4194304u    // NSPLIT x 4 MB f32 partials
#define PART_STRIDE 1048576ull

// round-to-nearest-even f32 -> bf16 bits
__device__ __forceinline__ unsigned short f2bf(float f) {
  unsigned u = __float_as_uint(f);
  return (unsigned short)((u + 0x7fffu + ((u >> 16) & 1u)) >> 16);
}

__device__ __forceinline__ void gload16(const void* g, void* l) {
  __builtin_amdgcn_global_load_lds((const __attribute__((address_space(1))) unsigned int*)g,
                                   (__attribute__((address_space(3))) unsigned int*)l, 16, 0, 0);
}

// ---------------------------------------------------------------------------
// prep: pack W into MFMA B-frags (bf16 hi/lo).
__global__ __launch_bounds__(256) void k_prep(const float* __restrict__ w,
                                              short8* __restrict__ wf) {
  const int kk   = blockIdx.x;
  const int nb   = threadIdx.x >> 6;
  const int lane = threadIdx.x & 63;
  const int n    = nb * 16 + (lane & 15);
  const int kb   = kk * 32 + (lane >> 4) * 8;
  const float4* wp = (const float4*)(w + (size_t)n * HID + kb);
  float4 f0 = wp[0], f1 = wp[1];
  float fv[8] = {f0.x, f0.y, f0.z, f0.w, f1.x, f1.y, f1.z, f1.w};
  short8 hi, lo;
#pragma unroll
  for (int j = 0; j < 8; ++j) {
    unsigned short h = f2bf(fv[j]);
    hi[j] = (short)h;
    float r = fv[j] - __uint_as_float((unsigned)h << 16);
    lo[j] = (short)f2bf(r);
  }
  size_t base = ((size_t)(kk * 4 + nb) * 2) * 64 + lane;
  wf[base] = hi;
  wf[base + 64] = lo;
}

// ---------------------------------------------------------------------------
// MFMA router GEMM (R8-exact, measured ~56us).
__global__ __launch_bounds__(256, 4) void k_gemm(const float* __restrict__ x,
                                                 const short8* __restrict__ wf,
                                                 float* __restrict__ part) {
  __shared__ short8 wl[2][512];   // 2 x 8 KB
  const int tid  = threadIdx.x;
  const int wv   = tid >> 6;
  const int lane = tid & 63;
  const int t0   = blockIdx.x * 64;
  const int k0   = blockIdx.y * KSZ;
  const int row  = t0 + wv * 16 + (lane & 15);

  const float* xp = x + (size_t)row * HID + k0 + (lane >> 4) * 8;
  const short8* wbase = wf + (size_t)(k0 >> 5) * 512;

  auto stage = [&](int c, int b) {
    const short8* src = wbase + (size_t)c * 512;
#pragma unroll
    for (int r = 0; r < 2; ++r) {
      const int o = r * 256 + wv * 64;       // wave-uniform LDS base
      gload16(src + o + lane, &wl[b][o]);    // lane*16B added by HW
    }
  };

  f32x4 acc[4] = {{0,0,0,0},{0,0,0,0},{0,0,0,0},{0,0,0,0}};

  stage(0, 0);
  __syncthreads();
  const int nch = KSZ >> 5;   // 32
  for (int c = 0; c < nch; ++c) {
    const int b = c & 1;
    if (c + 1 < nch) stage(c + 1, b ^ 1);

    const float4* xq = (const float4*)(xp + c * 32);
    float4 f0 = xq[0], f1 = xq[1];
    unsigned xb[8] = {__float_as_uint(f0.x), __float_as_uint(f0.y),
                      __float_as_uint(f0.z), __float_as_uint(f0.w),
                      __float_as_uint(f1.x), __float_as_uint(f1.y),
                      __float_as_uint(f1.z), __float_as_uint(f1.w)};
    union { unsigned u[4]; short8 s; } ua, ul;
#pragma unroll
    for (int p = 0; p < 4; ++p) {
      unsigned b0 = xb[2 * p], b1 = xb[2 * p + 1];
      ua.u[p] = __builtin_amdgcn_perm(b1, b0, 0x07060302u);
      float r0 = __uint_as_float(b0) - __uint_as_float(b0 & 0xffff0000u);
      float r1 = __uint_as_float(b1) - __uint_as_float(b1 & 0xffff0000u);
      unsigned t0b = __float_as_uint(r0), t1b = __float_as_uint(r1);
      t0b += 0x7fffu + ((t0b >> 16) & 1u);
      t1b += 0x7fffu + ((t1b >> 16) & 1u);
      ul.u[p] = __builtin_amdgcn_perm(t1b, t0b, 0x07060302u);
    }
    short8 ah = ua.s, al = ul.s;

#pragma unroll
    for (int nb = 0; nb < 4; ++nb) {
      short8 bh = wl[b][nb * 128 + lane];
      short8 bl = wl[b][nb * 128 + 64 + lane];
      acc[nb] = __builtin_amdgcn_mfma_f32_16x16x32_bf16(ah, bh, acc[nb], 0, 0, 0);
      acc[nb] = __builtin_amdgcn_mfma_f32_16x16x32_bf16(al, bh, acc[nb], 0, 0, 0);
      acc[nb] = __builtin_amdgcn_mfma_f32_16x16x32_bf16(ah, bl, acc[nb], 0, 0, 0);
    }
    __syncthreads();
  }

  float* p = part + (size_t)blockIdx.y * PART_STRIDE;
  const int mrow = t0 + wv * 16 + (lane >> 4) * 4;
  const int col  = lane & 15;
#pragma unroll
  for (int nb = 0; nb < 4; ++nb)
#pragma unroll
    for (int r = 0; r < 4; ++r)
      p[(size_t)(mrow + r) * 64 + nb * 16 + col] = acc[nb][r];
}

// ---------------------------------------------------------------------------
// Split-K reduce, 1024 blocks (R3-proven).
__global__ __launch_bounds__(256) void k_reduce(const float* __restrict__ part,
                                                float* __restrict__ out_logits) {
  unsigned i4 = blockIdx.x * 256u + threadIdx.x;
  const float4* p4 = (const float4*)part;
  float4 v = p4[i4];
#pragma unroll
  for (int s = 1; s < NSPLIT; ++s) {
    float4 a = p4[(size_t)s * (PART_STRIDE / 4) + i4];
    v.x += a.x; v.y += a.y; v.z += a.z; v.w += a.w;
  }
  ((float4*)out_logits)[i4] = v;
}

// ---------------------------------------------------------------------------
// Rowwise + in-block repair + BALLOT-BASED stable ranks (O(1)-depth):
// within a row the 8 experts are DISTINCT, so block-stable rank of (row r,
// expert e) = popcount of rows < r choosing e. Lane r of wave 0 keeps a
// 64-bit chosen-mask; after repair, 64 ballots give per-expert row-masks.
__global__ __launch_bounds__(256) void k_rowwise(const float* __restrict__ lg,
                                                 const float* __restrict__ x,
                                                 const float* __restrict__ w,
                                                 float* __restrict__ out,
                                                 float* __restrict__ psum,
                                                 float* __restrict__ lsqp,
                                                 int* __restrict__ flat,
                                                 int* __restrict__ rnk_g,
                                                 int* __restrict__ cbe) {
  __shared__ float tile[64][68];
  __shared__ float rmv[64], invv[64], val8s[64];
  __shared__ unsigned long long Bmask[64];
  __shared__ int   fl_rows[64];
  __shared__ int   fl_n;
  __shared__ unsigned long long candmask;
  __shared__ double cexact[64];
  const int bid  = blockIdx.x;
  const int tid  = threadIdx.x;
  const int wv   = tid >> 6;
  const int lane = tid & 63;
  const int t0   = bid * 64;
  if (tid == 0) fl_n = 0;

  {
    const size_t boff = (size_t)bid * 4096;
#pragma unroll
    for (int k = 0; k < 16; ++k) {
      int idx = k * 256 + tid;
      tile[idx >> 6][idx & 63] = lg[boff + idx];
    }
  }
  __syncthreads();

  if (wv == 1) {
    const int r = lane;
    float rm = -3.0e38f;
#pragma unroll
    for (int c4 = 0; c4 < 16; ++c4) {
      float4 f = *(float4*)&tile[r][c4 * 4];
      rm = fmaxf(rm, fmaxf(fmaxf(f.x, f.y), fmaxf(f.z, f.w)));
    }
    float se = 0.0f;
#pragma unroll
    for (int c4 = 0; c4 < 16; ++c4) {
      float4 f = *(float4*)&tile[r][c4 * 4];
      se += expf(f.x - rm) + expf(f.y - rm) + expf(f.z - rm) + expf(f.w - rm);
    }
    rmv[r] = rm; invv[r] = 1.0f / se;
    float lse = rm + logf(se);
    float l2 = lse * lse;
#pragma unroll
    for (int o = 32; o > 0; o >>= 1) l2 += __shfl_down(l2, o);
    if (lane == 0) lsqp[bid] = l2;
  }
  __syncthreads();

  unsigned long long chosen = 0ull;   // wave-0 lane r: bitmask of row r's experts
  int myidx[8];                        // wave-0 lane r: its 8 expert ids (slot order)
  if (wv == 0) {
    const unsigned t = t0 + lane;
    float val[9]; int idx[9];
#pragma unroll
    for (int j = 0; j < 9; ++j) { val[j] = -3.0e38f; idx[j] = 0; }
    bool flag = false;
#pragma unroll
    for (int c4 = 0; c4 < 16; ++c4) {
      float4 f = *(float4*)&tile[lane][c4 * 4];
      float fe[4] = {f.x, f.y, f.z, f.w};
#pragma unroll
      for (int jj = 0; jj < 4; ++jj) {
        float v = fe[jj];
        flag = flag || (fabsf(fabsf(v) - 2.0f) < EPS);
        float c = fminf(fmaxf(v, -2.0f), 2.0f);
        int id = c4 * 4 + jj;
#pragma unroll
        for (int j = 0; j < 9; ++j) {
          bool sw = c > val[j];
          float tv = sw ? val[j] : c; int ti = sw ? idx[j] : id;
          val[j] = sw ? c : val[j];   idx[j] = sw ? id : idx[j];
          c = tv; id = ti;
        }
      }
    }
    val8s[lane] = val[8];
#pragma unroll
    for (int j = 0; j < 8; ++j) {
      float gap = val[j] - val[j + 1];
      bool bothclip = (val[j] == val[j + 1]) && (fabsf(val[j]) == 2.0f);
      flag = flag || (gap < EPS && !bothclip);
    }
    if (!flag) {
      float m = val[0], pe[8], sum = 0.0f;
#pragma unroll
      for (int j = 0; j < 8; ++j) { pe[j] = expf(val[j] - m); sum += pe[j]; }
      float inv = 1.0f / sum;
      *(float4*)&out[O_PROBS + (size_t)t * 8]     = make_float4(pe[0]*inv, pe[1]*inv, pe[2]*inv, pe[3]*inv);
      *(float4*)&out[O_PROBS + (size_t)t * 8 + 4] = make_float4(pe[4]*inv, pe[5]*inv, pe[6]*inv, pe[7]*inv);
      *(float4*)&out[O_TIDX + (size_t)t * 8]      = make_float4((float)idx[0], (float)idx[1], (float)idx[2], (float)idx[3]);
      *(float4*)&out[O_TIDX + (size_t)t * 8 + 4]  = make_float4((float)idx[4], (float)idx[5], (float)idx[6], (float)idx[7]);
      *(int4*)&flat[(size_t)t * 8]     = make_int4(idx[0], idx[1], idx[2], idx[3]);
      *(int4*)&flat[(size_t)t * 8 + 4] = make_int4(idx[4], idx[5], idx[6], idx[7]);
#pragma unroll
      for (int j = 0; j < 8; ++j) { myidx[j] = idx[j]; chosen |= 1ull << idx[j]; }
    } else {
      int sl = atomicAdd(&fl_n, 1);
      fl_rows[sl] = lane;
    }
  } else if (wv == 2 || wv == 3) {
    const int e = lane, half = wv - 2;
    float s = 0.0f;
#pragma unroll
    for (int r = 0; r < 32; ++r) {
      int rr = half * 32 + r;
      s += expf(tile[rr][e] - rmv[rr]) * invv[rr];
    }
    psum[(size_t)bid * 128 + half * 64 + e] = s;
  }
  __syncthreads();

  // ---- in-block repair of flagged rows (candidate-limited exact f64) ----
  for (int i = 0; i < fl_n; ++i) {
    const int r = fl_rows[i];
    if (wv == 0) {
      float c = fminf(fmaxf(tile[r][lane], -2.0f), 2.0f);
      bool cnd = (c >= val8s[r] - 3.0f * EPS);
      unsigned long long m = __ballot(cnd);
      if (lane == 0) candmask = m;
    }
    __syncthreads();
    const unsigned long long m = candmask;
    const float* xr = x + (size_t)(t0 + r) * HID;
    {
      int ord = 0;
      for (int e = 0; e < 64; ++e) {
        if ((m >> e) & 1ull) {
          if ((ord & 3) == wv) {
            const float* wr = w + (size_t)e * HID;
            double p0 = 0.0, p1 = 0.0, p2 = 0.0, p3 = 0.0;
            const int kb = lane * 64;
            for (int k = kb; k < kb + 64; k += 4) {
              float4 xv = *(const float4*)&xr[k];
              float4 wv4 = *(const float4*)&wr[k];
              p0 = fma((double)xv.x, (double)wv4.x, p0);
              p1 = fma((double)xv.y, (double)wv4.y, p1);
              p2 = fma((double)xv.z, (double)wv4.z, p2);
              p3 = fma((double)xv.w, (double)wv4.w, p3);
            }
            double p = (p0 + p1) + (p2 + p3);
#pragma unroll
            for (int o = 32; o > 0; o >>= 1) p += __shfl_down(p, o);
            if (lane == 0) cexact[e] = fmin(fmax(p, -2.0), 2.0);
          }
          ord++;
        }
      }
    }
    __syncthreads();
    if (tid == r) {   // wave-0 lane r
      double val[8]; int idx[8];
#pragma unroll
      for (int j = 0; j < 8; ++j) { val[j] = -1.0e300; idx[j] = 0; }
      for (int e = 0; e < 64; ++e) {
        if (!((m >> e) & 1ull)) continue;
        double c = cexact[e];
        int id = e;
#pragma unroll
        for (int j = 0; j < 8; ++j) {
          bool sw = c > val[j];
          double tv = sw ? val[j] : c; int ti = sw ? idx[j] : id;
          val[j] = sw ? c : val[j];    idx[j] = sw ? id : idx[j];
          c = tv; id = ti;
        }
      }
      float mm = (float)val[0], pe[8], sum = 0.0f;
#pragma unroll
      for (int j = 0; j < 8; ++j) { pe[j] = expf((float)val[j] - mm); sum += pe[j]; }
      float inv = 1.0f / sum;
      const unsigned t = t0 + r;
      chosen = 0ull;
#pragma unroll
      for (int j = 0; j < 8; ++j) {
        out[O_PROBS + (size_t)t * 8 + j] = pe[j] * inv;
        out[O_TIDX  + (size_t)t * 8 + j] = (float)idx[j];
        flat[(size_t)t * 8 + j] = idx[j];
        myidx[j] = idx[j];
        chosen |= 1ull << idx[j];
      }
    }
    __syncthreads();
  }

  // ---- ballot-based ranks + counts (wave 0 only; 64 ballots, O(1) depth) ----
  if (wv == 0) {
    for (int e = 0; e < 64; ++e) {
      unsigned long long b = __ballot((chosen >> e) & 1ull);
      if (lane == 0) Bmask[e] = b;
    }
    __builtin_amdgcn_wave_barrier();
    const unsigned long long below = (lane == 0) ? 0ull : (~0ull >> (64 - lane));
    int rr[8];
#pragma unroll
    for (int j = 0; j < 8; ++j)
      rr[j] = (int)__popcll(Bmask[myidx[j]] & below);
    *(int4*)&rnk_g[(size_t)bid * 512 + lane * 8]     = make_int4(rr[0], rr[1], rr[2], rr[3]);
    *(int4*)&rnk_g[(size_t)bid * 512 + lane * 8 + 4] = make_int4(rr[4], rr[5], rr[6], rr[7]);
    cbe[bid * 64 + lane] = (int)__popcll(Bmask[lane]);
  }
}

// ---------------------------------------------------------------------------
// Scan + finalize, segmented: thread (e, g) owns 64 blocks. 3 passes of
// 64-iteration loops (vs R18's 256-serial). 1 block x 256 thr.
__global__ __launch_bounds__(256) void k_scan(const int* __restrict__ cbe,
                                              const float* __restrict__ psum,
                                              const float* __restrict__ lsqp,
                                              int* __restrict__ pref,
                                              float* __restrict__ out) {
  __shared__ int part4[4][64];   // per-segment expert counts
  __shared__ int segb[4][64];    // per-segment expert bases
  __shared__ int ctot[64];
  __shared__ float gsum[4][64];
  const int tid = threadIdx.x;
  const int e = tid & 63, g = tid >> 6;

  float ps = 0.0f;
  int cs = 0;
  for (int b = g * 64; b < g * 64 + 64; ++b) {
    ps += psum[(size_t)b * 128 + e] + psum[(size_t)b * 128 + 64 + e];
    cs += cbe[b * 64 + e];
  }
  gsum[g][e] = ps;
  part4[g][e] = cs;
  __syncthreads();

  if (tid < 64) {
    ctot[tid] = part4[0][tid] + part4[1][tid] + part4[2][tid] + part4[3][tid];
  }
  __syncthreads();

  if (tid < 64) {
    int incl = 0;
    for (int i = 0; i <= tid; ++i) incl += ctot[i];
    const int tpe = ctot[tid];
    out[O_TPE + tid]   = (float)tpe;
    out[O_GROUP + tid] = (float)incl;
    int base = incl - tpe;
    for (int gg = 0; gg < 4; ++gg) { segb[gg][tid] = base; base += part4[gg][tid]; }

    float pst = (gsum[0][tid] + gsum[1][tid]) + (gsum[2][tid] + gsum[3][tid]);
    float term = ((float)tpe / 131072.0f) * (pst / 16384.0f) * 64.0f;
#pragma unroll
    for (int o2 = 32; o2 > 0; o2 >>= 1) term += __shfl_down(term, o2);
    float zs = (lsqp[tid * 4] + lsqp[tid * 4 + 1]) + (lsqp[tid * 4 + 2] + lsqp[tid * 4 + 3]);
#pragma unroll
    for (int o2 = 32; o2 > 0; o2 >>= 1) zs += __shfl_down(zs, o2);
    if (tid == 0) { out[O_LB] = term; out[O_ZL] = zs / 16384.0f; }
  }
  __syncthreads();

  int run = segb[g][e];
  for (int b = g * 64; b < g * 64 + 64; ++b) {
    pref[b * 64 + e] = run;
    run += cbe[b * 64 + e];
  }
}

// ---------------------------------------------------------------------------
// Elementwise scatter: pos = pref[block][e] + rank. 512 blocks x 256 thr.
__global__ __launch_bounds__(256) void k_scatter(const int* __restrict__ flat,
                                                 const int* __restrict__ rnk,
                                                 const int* __restrict__ pref,
                                                 float* __restrict__ out) {
  const int j = blockIdx.x * 256 + threadIdx.x;
  const int e = flat[j];
  const int pos = pref[(j >> 9) * 64 + e] + rnk[j];
  out[O_IDX + pos] = (float)j;
}

// ---------------------------------------------------------------------------
extern "C" void kernel_launch(void* const* d_in, const int* in_sizes, int n_in,
                              void* d_out, int out_size, void* d_ws, size_t ws_size,
                              hipStream_t stream) {
  (void)in_sizes; (void)n_in; (void)out_size; (void)ws_size;
  const float* x  = (const float*)d_in[0];
  const float* Wm = (const float*)d_in[1];
  float* out = (float*)d_out;
  char*  ws  = (char*)d_ws;

  float*  lsqp   = (float*)(ws + W_LSQP);
  int*    cbe    = (int*)(ws + W_CBE);
  int*    pref   = (int*)(ws + W_PREF);
  float*  psum   = (float*)(ws + W_PSUM);
  int*    flat   = (int*)(ws + W_FLAT);
  int*    rnk    = (int*)(ws + W_RNK);
  short8* wf     = (short8*)(ws + W_WF);
  float*  part   = (float*)(ws + W_PART);

  k_prep   <<<dim3(128),  dim3(256), 0, stream>>>(Wm, wf);
  k_gemm   <<<dim3(NTOK / 64, NSPLIT), dim3(256), 0, stream>>>(x, wf, part);
  k_reduce <<<dim3(1024), dim3(256), 0, stream>>>(part, out + O_LOGITS);
  k_rowwise<<<dim3(256),  dim3(256), 0, stream>>>(out + O_LOGITS, x, Wm, out, psum, lsqp, flat, rnk, cbe);
  k_scan   <<<dim3(1),    dim3(256), 0, stream>>>(cbe, psum, lsqp, pref, out);
  k_scatter<<<dim3(512),  dim3(256), 0, stream>>>(flat, rnk, pref, out);
}